// Round 10
// baseline (79.641 us; speedup 1.0000x reference)
//
#include <hip/hip_runtime.h>

#define CDIM 256
#define NDET 900
#define NMAP 100
#define NPTS 20
#define PH 8
#define NDB 113              // ceil(900/8)
#define NMB 13               // ceil(100/8)
#define MAP_ROW0 904

__device__ __forceinline__ const float* lvlPtr(int l, const float* p2, const float* p3,
                                               const float* p4, const float* p5) {
    return (l == 0) ? p2 : (l == 1) ? p3 : (l == 2) ? p4 : p5;
}
__device__ __forceinline__ int lvlHW(int l) {
    return (l == 0) ? 19200 : (l == 1) ? 4800 : (l == 2) ? 1200 : 300;
}

// ---------------- Kernel G: projection setup + multiscale gather ----------------
__global__ __launch_bounds__(256, 4) void g_setup_gather(
    const float* __restrict__ p2, const float* __restrict__ p3,
    const float* __restrict__ p4, const float* __restrict__ p5,
    const float* __restrict__ Kin, const float* __restrict__ Ein,
    const float* __restrict__ det3d, const float* __restrict__ mapanch,
    float* __restrict__ aggw)
{
    const int pt = blockIdx.x;      // 0..999
    const int t  = threadIdx.x;
    const bool isDet = (pt < NDET);
    const int m = pt - NDET;

    __shared__ int   s_off[25][4];
    __shared__ float s_w[25][4];
    __shared__ int   s_list[32];
    __shared__ int   s_n;

    if (t < 25) {
        float h0, h1, h2;
        if (isDet) {
            h0 = det3d[pt * 3 + 0];
            h1 = det3d[pt * 3 + 1];
            h2 = det3d[pt * 3 + 2];
        } else {
            float cx = 0.f, cy = 0.f;
            #pragma unroll
            for (int j = 0; j < NPTS; ++j) {
                cx += mapanch[(m * NPTS + j) * 2 + 0];
                cy += mapanch[(m * NPTS + j) * 2 + 1];
            }
            h0 = cx / (float)NPTS;
            h1 = cy / (float)NPTS;
            h2 = 0.f;
        }

        bool pred = false;
        if (t < 24) {
            const int cam = t >> 2, l = t & 3;
            float pc[3];
            #pragma unroll
            for (int i = 0; i < 3; ++i) {
                pc[i] = Ein[cam * 16 + i * 4 + 0] * h0
                      + Ein[cam * 16 + i * 4 + 1] * h1
                      + Ein[cam * 16 + i * 4 + 2] * h2
                      + Ein[cam * 16 + i * 4 + 3] * 1.f;
            }
            const float q0 = Kin[cam*9+0]*pc[0] + Kin[cam*9+1]*pc[1] + Kin[cam*9+2]*pc[2];
            const float q1 = Kin[cam*9+3]*pc[0] + Kin[cam*9+4]*pc[1] + Kin[cam*9+5]*pc[2];
            const float q2 = Kin[cam*9+6]*pc[0] + Kin[cam*9+7]*pc[1] + Kin[cam*9+8]*pc[2];
            const float depth = q2;
            const float u = q0 / (depth + 1e-6f);
            const float v = q1 / (depth + 1e-6f);
            const bool valid = (depth > 0.1f);
            const float gx = u / 640.0f * 2.0f - 1.0f;
            const float gy = v / 480.0f * 2.0f - 1.0f;

            const int Hs[4] = {120, 60, 30, 15};
            const int Ws[4] = {160, 80, 40, 20};
            const int H = Hs[l], W = Ws[l];
            const float x = (gx + 1.f) * (W * 0.5f) - 0.5f;
            const float y = (gy + 1.f) * (H * 0.5f) - 0.5f;
            const float x0f = floorf(x), y0f = floorf(y);
            const float wx1 = x - x0f, wx0 = 1.f - wx1;
            const float wy1 = y - y0f, wy0 = 1.f - wy1;
            const float x1f = x0f + 1.f, y1f = y0f + 1.f;
            const bool bx0 = (x0f >= 0.f) && (x0f <= (float)(W - 1));
            const bool bx1 = (x1f >= 0.f) && (x1f <= (float)(W - 1));
            const bool by0 = (y0f >= 0.f) && (y0f <= (float)(H - 1));
            const bool by1 = (y1f >= 0.f) && (y1f <= (float)(H - 1));
            const int xc0 = (int)fminf(fmaxf(x0f, 0.f), (float)(W - 1));
            const int xc1 = (int)fminf(fmaxf(x1f, 0.f), (float)(W - 1));
            const int yc0 = (int)fminf(fmaxf(y0f, 0.f), (float)(H - 1));
            const int yc1 = (int)fminf(fmaxf(y1f, 0.f), (float)(H - 1));
            const int base = cam * CDIM * H * W;
            s_off[t][0] = base + yc0 * W + xc0;
            s_off[t][1] = base + yc0 * W + xc1;
            s_off[t][2] = base + yc1 * W + xc0;
            s_off[t][3] = base + yc1 * W + xc1;
            const float w0 = (bx0 && by0) ? wx0 * wy0 : 0.f;
            const float w1 = (bx1 && by0) ? wx1 * wy0 : 0.f;
            const float w2 = (bx0 && by1) ? wx0 * wy1 : 0.f;
            const float w3 = (bx1 && by1) ? wx1 * wy1 : 0.f;
            s_w[t][0] = w0; s_w[t][1] = w1; s_w[t][2] = w2; s_w[t][3] = w3;
            pred = valid && ((w0 + w1 + w2 + w3) != 0.f);
        } else {
            s_off[24][0] = 0; s_off[24][1] = 0; s_off[24][2] = 0; s_off[24][3] = 0;
            s_w[24][0] = 0.f; s_w[24][1] = 0.f; s_w[24][2] = 0.f; s_w[24][3] = 0.f;
        }

        const unsigned long long mask = __ballot(pred);
        const int n = __popcll(mask);
        const int rank = __popcll(mask & ((1ull << t) - 1ull));
        if (pred) s_list[rank] = t;
        const int npad = (n + 7) & ~7;
        if (t < 8 && (n + t) < npad) s_list[n + t] = 24;
        if (t == 0) s_n = npad;
    }
    __syncthreads();

    float acc = 0.f;
    const int npad = s_n;
    for (int base = 0; base < npad; base += 8) {
        float v[8][4];
        int tj[8];
        #pragma unroll
        for (int j = 0; j < 8; ++j) {
            const int tt = s_list[base + j];
            tj[j] = tt;
            const int l = tt & 3;
            const float* f = lvlPtr(l, p2, p3, p4, p5);
            const int cHW = t * lvlHW(l);
            v[j][0] = f[s_off[tt][0] + cHW];
            v[j][1] = f[s_off[tt][1] + cHW];
            v[j][2] = f[s_off[tt][2] + cHW];
            v[j][3] = f[s_off[tt][3] + cHW];
        }
        #pragma unroll
        for (int j = 0; j < 8; ++j) {
            const int tt = tj[j];
            acc += s_w[tt][0] * v[j][0] + s_w[tt][1] * v[j][1]
                 + s_w[tt][2] * v[j][2] + s_w[tt][3] * v[j][3];
        }
    }
    const float aggv = (acc * 0.25f) / 6.0f;
    const int row = isDet ? pt : (MAP_ROW0 + m);
    aggw[row * CDIM + t] = aggv;
}

// ---------------- Kernel H: hidden GEMM (8 points/block) + heads ----------------
__global__ __launch_bounds__(256, 4) void h_mlp_heads(
    const float* __restrict__ aggw,
    const float* __restrict__ W1d, const float* __restrict__ b1d,
    const float* __restrict__ Wcd, const float* __restrict__ bcd,
    const float* __restrict__ Wod, const float* __restrict__ bod,
    const float* __restrict__ W1m, const float* __restrict__ b1m,
    const float* __restrict__ Wcm, const float* __restrict__ bcm,
    const float* __restrict__ Wom, const float* __restrict__ bom,
    const float* __restrict__ detfull, const float* __restrict__ mapanch,
    float* __restrict__ out)
{
    const int b = blockIdx.x;       // 0..112 det, 113..125 map
    const int t = threadIdx.x;
    const bool isDet = (b < NDB);
    const int pb = isDet ? b * PH : (b - NDB) * PH;   // point base within class
    const int r0 = isDet ? pb : (MAP_ROW0 + pb);      // agg row base
    const int vlim = isDet ? (NDET - pb) : (NMAP - pb);

    __shared__ float s_hid[PH][CDIM];

    const float* __restrict__ W1 = isDet ? W1d : W1m;
    const float bb = (isDet ? b1d : b1m)[t];
    float hs[PH];
    #pragma unroll
    for (int p = 0; p < PH; ++p) hs[p] = bb;

    const float4* __restrict__ A4 = (const float4*)(aggw + r0 * CDIM);  // [PH][64]

    float wvA[16], wvB[16];
    #pragma unroll
    for (int i = 0; i < 16; ++i) wvA[i] = W1[i * CDIM + t];
    #pragma unroll
    for (int k0 = 0; k0 < CDIM; k0 += 32) {
        #pragma unroll
        for (int i = 0; i < 16; ++i) wvB[i] = W1[(k0 + 16 + i) * CDIM + t];
        #pragma unroll
        for (int i4 = 0; i4 < 4; ++i4) {
            #pragma unroll
            for (int p = 0; p < PH; ++p) {
                const float4 a = A4[p * 64 + (k0 >> 2) + i4];
                hs[p] = fmaf(a.x, wvA[i4 * 4 + 0], hs[p]);
                hs[p] = fmaf(a.y, wvA[i4 * 4 + 1], hs[p]);
                hs[p] = fmaf(a.z, wvA[i4 * 4 + 2], hs[p]);
                hs[p] = fmaf(a.w, wvA[i4 * 4 + 3], hs[p]);
            }
        }
        if (k0 + 32 < CDIM) {
            #pragma unroll
            for (int i = 0; i < 16; ++i) wvA[i] = W1[(k0 + 32 + i) * CDIM + t];
        }
        #pragma unroll
        for (int i4 = 0; i4 < 4; ++i4) {
            #pragma unroll
            for (int p = 0; p < PH; ++p) {
                const float4 a = A4[p * 64 + ((k0 + 16) >> 2) + i4];
                hs[p] = fmaf(a.x, wvB[i4 * 4 + 0], hs[p]);
                hs[p] = fmaf(a.y, wvB[i4 * 4 + 1], hs[p]);
                hs[p] = fmaf(a.z, wvB[i4 * 4 + 2], hs[p]);
                hs[p] = fmaf(a.w, wvB[i4 * 4 + 3], hs[p]);
            }
        }
    }
    #pragma unroll
    for (int p = 0; p < PH; ++p) s_hid[p][t] = fmaxf(hs[p], 0.f);
    __syncthreads();

    // heads: 16 lanes per output, weights loaded once, reused for 8 points
    const int grp = t >> 4;
    const int ln  = t & 15;
    const int nOut = isDet ? 15 : 43;
    const int nrep = isDet ? 1 : 3;
    for (int rep = 0; rep < nrep; ++rep) {
        const int o = grp + rep * 16;
        if (o < nOut) {
            const float* Wp; int stride, oo;
            if (isDet) {
                if (o < 4) { Wp = Wcd; stride = 4;  oo = o; }
                else       { Wp = Wod; stride = 11; oo = o - 4; }
            } else {
                if (o < 3) { Wp = Wcm; stride = 3;  oo = o; }
                else       { Wp = Wom; stride = 40; oo = o - 3; }
            }
            float wv[16];
            #pragma unroll
            for (int kk = 0; kk < 16; ++kk) wv[kk] = Wp[(ln + kk * 16) * stride + oo];
            for (int p = 0; p < PH; ++p) {
                float sp = 0.f;
                #pragma unroll
                for (int kk = 0; kk < 16; ++kk) {
                    sp = fmaf(s_hid[p][ln + kk * 16], wv[kk], sp);
                }
                #pragma unroll
                for (int off = 1; off < 16; off <<= 1) sp += __shfl_xor(sp, off, 64);
                if (ln == 0 && p < vlim) {
                    float bias; int ooff;
                    if (isDet) {
                        const int pa = pb + p;
                        if (o < 4) { bias = bcd[oo];                         ooff = pa * 4 + oo; }
                        else       { bias = bod[oo] + detfull[pa * 11 + oo]; ooff = 3600 + pa * 11 + oo; }
                    } else {
                        const int mi = pb + p;
                        if (o < 3) { bias = bcm[oo];                         ooff = 13500 + mi * 3 + oo; }
                        else       { bias = bom[oo] + mapanch[mi * 40 + oo]; ooff = 13800 + mi * 40 + oo; }
                    }
                    out[ooff] = sp + bias;
                }
            }
        }
    }
}

extern "C" void kernel_launch(void* const* d_in, const int* in_sizes, int n_in,
                              void* d_out, int out_size, void* d_ws, size_t ws_size,
                              hipStream_t stream) {
    const float* p2      = (const float*)d_in[0];
    const float* p3      = (const float*)d_in[1];
    const float* p4      = (const float*)d_in[2];
    const float* p5      = (const float*)d_in[3];
    const float* Kin     = (const float*)d_in[4];
    const float* Ein     = (const float*)d_in[5];
    const float* det3d   = (const float*)d_in[6];
    const float* detfull = (const float*)d_in[7];
    const float* mapanch = (const float*)d_in[8];
    const float* W1d     = (const float*)d_in[9];
    const float* b1d     = (const float*)d_in[10];
    const float* Wcd     = (const float*)d_in[11];
    const float* bcd     = (const float*)d_in[12];
    const float* Wod     = (const float*)d_in[13];
    const float* bod     = (const float*)d_in[14];
    const float* W1m     = (const float*)d_in[15];
    const float* b1m     = (const float*)d_in[16];
    const float* Wcm     = (const float*)d_in[17];
    const float* bcm     = (const float*)d_in[18];
    const float* Wom     = (const float*)d_in[19];
    const float* bom     = (const float*)d_in[20];
    float* out = (float*)d_out;
    float* aggw = (float*)d_ws;   // 1008 x 256 floats ≈ 1 MB

    g_setup_gather<<<NDET + NMAP, 256, 0, stream>>>(
        p2, p3, p4, p5, Kin, Ein, det3d, mapanch, aggw);

    h_mlp_heads<<<NDB + NMB, 256, 0, stream>>>(
        aggw, W1d, b1d, Wcd, bcd, Wod, bod, W1m, b1m, Wcm, bcm, Wom, bom,
        detfull, mapanch, out);
}

// Round 11
// 54.271 us; speedup vs baseline: 1.4675x; 1.4675x over previous
//
#include <hip/hip_runtime.h>

#define CDIM 256
#define NDET 900
#define NMAP 100
#define NPTS 20
#define NBLK (NDET + NMAP)
#define P5OFF 1843200   // 6*30*40*256

// ---------- Kernel T: pack levels 2,3 into ws as [cam][H][W][C] ----------
__global__ __launch_bounds__(256) void t_pack(
    const float* __restrict__ p4, const float* __restrict__ p5,
    float* __restrict__ wsf)
{
    const int b = blockIdx.x;   // 0..179: p4 rows; 180..269: p5 rows
    const int t = threadIdx.x;  // channel
    if (b < 180) {
        const int cam = b / 30, h = b % 30;
        const float* src = p4 + ((cam * CDIM + t) * 30 + h) * 40;
        float* dst = wsf + ((cam * 30 + h) * 40) * CDIM + t;
        #pragma unroll
        for (int w = 0; w < 40; ++w) dst[w * CDIM] = src[w];
    } else {
        const int bb = b - 180;
        const int cam = bb / 15, h = bb % 15;
        const float* src = p5 + ((cam * CDIM + t) * 15 + h) * 20;
        float* dst = wsf + P5OFF + ((cam * 15 + h) * 20) * CDIM + t;
        #pragma unroll
        for (int w = 0; w < 20; ++w) dst[w * CDIM] = src[w];
    }
}

// ---------- Kernel F: fused setup + gather + MLP + heads ----------
__global__ __launch_bounds__(256, 4) void autonav_fused(
    const float* __restrict__ p2, const float* __restrict__ p3,
    const float* __restrict__ wsf,
    const float* __restrict__ Kin, const float* __restrict__ Ein,
    const float* __restrict__ det3d, const float* __restrict__ detfull,
    const float* __restrict__ mapanch,
    const float* __restrict__ W1d, const float* __restrict__ b1d,
    const float* __restrict__ Wcd, const float* __restrict__ bcd,
    const float* __restrict__ Wod, const float* __restrict__ bod,
    const float* __restrict__ W1m, const float* __restrict__ b1m,
    const float* __restrict__ Wcm, const float* __restrict__ bcm,
    const float* __restrict__ Wom, const float* __restrict__ bom,
    float* __restrict__ out)
{
    const int pt = blockIdx.x;      // 0..999
    const int t  = threadIdx.x;
    const bool isDet = (pt < NDET);
    const int m = pt - NDET;

    __shared__ int   s_off[25][4];
    __shared__ float s_w[25][4];
    __shared__ int   s_list[32];
    __shared__ int   s_n;
    __shared__ float s_vec[CDIM];
    __shared__ float s_hid[CDIM];

    if (t < 25) {
        float h0, h1, h2;
        if (isDet) {
            h0 = det3d[pt * 3 + 0];
            h1 = det3d[pt * 3 + 1];
            h2 = det3d[pt * 3 + 2];
        } else {
            float cx = 0.f, cy = 0.f;
            #pragma unroll
            for (int j = 0; j < NPTS; ++j) {
                cx += mapanch[(m * NPTS + j) * 2 + 0];
                cy += mapanch[(m * NPTS + j) * 2 + 1];
            }
            h0 = cx / (float)NPTS;
            h1 = cy / (float)NPTS;
            h2 = 0.f;
        }

        bool pred = false;
        if (t < 24) {
            const int cam = t >> 2, l = t & 3;
            float pc[3];
            #pragma unroll
            for (int i = 0; i < 3; ++i) {
                pc[i] = Ein[cam * 16 + i * 4 + 0] * h0
                      + Ein[cam * 16 + i * 4 + 1] * h1
                      + Ein[cam * 16 + i * 4 + 2] * h2
                      + Ein[cam * 16 + i * 4 + 3] * 1.f;
            }
            const float q0 = Kin[cam*9+0]*pc[0] + Kin[cam*9+1]*pc[1] + Kin[cam*9+2]*pc[2];
            const float q1 = Kin[cam*9+3]*pc[0] + Kin[cam*9+4]*pc[1] + Kin[cam*9+5]*pc[2];
            const float q2 = Kin[cam*9+6]*pc[0] + Kin[cam*9+7]*pc[1] + Kin[cam*9+8]*pc[2];
            const float depth = q2;
            const float u = q0 / (depth + 1e-6f);
            const float v = q1 / (depth + 1e-6f);
            const bool valid = (depth > 0.1f);
            const float gx = u / 640.0f * 2.0f - 1.0f;
            const float gy = v / 480.0f * 2.0f - 1.0f;

            const int Hs[4] = {120, 60, 30, 15};
            const int Ws[4] = {160, 80, 40, 20};
            const int H = Hs[l], W = Ws[l];
            const float x = (gx + 1.f) * (W * 0.5f) - 0.5f;
            const float y = (gy + 1.f) * (H * 0.5f) - 0.5f;
            const float x0f = floorf(x), y0f = floorf(y);
            const float wx1 = x - x0f, wx0 = 1.f - wx1;
            const float wy1 = y - y0f, wy0 = 1.f - wy1;
            const float x1f = x0f + 1.f, y1f = y0f + 1.f;
            const bool bx0 = (x0f >= 0.f) && (x0f <= (float)(W - 1));
            const bool bx1 = (x1f >= 0.f) && (x1f <= (float)(W - 1));
            const bool by0 = (y0f >= 0.f) && (y0f <= (float)(H - 1));
            const bool by1 = (y1f >= 0.f) && (y1f <= (float)(H - 1));
            const int xc0 = (int)fminf(fmaxf(x0f, 0.f), (float)(W - 1));
            const int xc1 = (int)fminf(fmaxf(x1f, 0.f), (float)(W - 1));
            const int yc0 = (int)fminf(fmaxf(y0f, 0.f), (float)(H - 1));
            const int yc1 = (int)fminf(fmaxf(y1f, 0.f), (float)(H - 1));
            if (l < 2) {
                // original channel-major layout; gather adds t*HW
                const int base = cam * CDIM * H * W;
                s_off[t][0] = base + yc0 * W + xc0;
                s_off[t][1] = base + yc0 * W + xc1;
                s_off[t][2] = base + yc1 * W + xc0;
                s_off[t][3] = base + yc1 * W + xc1;
            } else {
                // packed [cam][H][W][C] in ws; gather adds t
                const int pb = (l == 2 ? 0 : P5OFF) + cam * H * W * CDIM;
                s_off[t][0] = pb + (yc0 * W + xc0) * CDIM;
                s_off[t][1] = pb + (yc0 * W + xc1) * CDIM;
                s_off[t][2] = pb + (yc1 * W + xc0) * CDIM;
                s_off[t][3] = pb + (yc1 * W + xc1) * CDIM;
            }
            const float w0 = (bx0 && by0) ? wx0 * wy0 : 0.f;
            const float w1 = (bx1 && by0) ? wx1 * wy0 : 0.f;
            const float w2 = (bx0 && by1) ? wx0 * wy1 : 0.f;
            const float w3 = (bx1 && by1) ? wx1 * wy1 : 0.f;
            s_w[t][0] = w0; s_w[t][1] = w1; s_w[t][2] = w2; s_w[t][3] = w3;
            pred = valid && ((w0 + w1 + w2 + w3) != 0.f);
        } else {
            s_off[24][0] = 0; s_off[24][1] = 0; s_off[24][2] = 0; s_off[24][3] = 0;
            s_w[24][0] = 0.f; s_w[24][1] = 0.f; s_w[24][2] = 0.f; s_w[24][3] = 0.f;
        }

        const unsigned long long mask = __ballot(pred);
        const int n = __popcll(mask);
        const int rank = __popcll(mask & ((1ull << t) - 1ull));
        if (pred) s_list[rank] = t;
        const int npad = (n + 7) & ~7;
        if (t < 8 && (n + t) < npad) s_list[n + t] = 24;
        if (t == 0) s_n = npad;
    }
    __syncthreads();

    // ---- gather: branch-free chunks of 8 tiles; lvl2/3 coalesced from ws ----
    float acc = 0.f;
    const int npad = s_n;
    for (int base = 0; base < npad; base += 8) {
        float v[8][4];
        int tj[8];
        #pragma unroll
        for (int j = 0; j < 8; ++j) {
            const int tt = s_list[base + j];
            tj[j] = tt;
            const int l = tt & 3;
            const float* f = (l == 0) ? p2 : (l == 1) ? p3 : wsf;
            const int coff = (l == 0) ? t * 19200 : (l == 1) ? t * 4800 : t;
            v[j][0] = f[s_off[tt][0] + coff];
            v[j][1] = f[s_off[tt][1] + coff];
            v[j][2] = f[s_off[tt][2] + coff];
            v[j][3] = f[s_off[tt][3] + coff];
        }
        #pragma unroll
        for (int j = 0; j < 8; ++j) {
            const int tt = tj[j];
            acc += s_w[tt][0] * v[j][0] + s_w[tt][1] * v[j][1]
                 + s_w[tt][2] * v[j][2] + s_w[tt][3] * v[j][3];
        }
    }
    const float agg = (acc * 0.25f) / 6.0f;

    s_vec[t] = agg;
    __syncthreads();

    // ---- hidden GEMV: double-buffered 32-deep W1 batches ----
    const float* __restrict__ W1 = isDet ? W1d : W1m;
    const float* __restrict__ b1 = isDet ? b1d : b1m;
    float hsum = b1[t];
    const float4* sv4 = (const float4*)s_vec;
    float wvA[32], wvB[32];
    #pragma unroll
    for (int i = 0; i < 32; ++i) wvA[i] = W1[i * CDIM + t];
    #pragma unroll
    for (int k0 = 0; k0 < CDIM; k0 += 64) {
        #pragma unroll
        for (int i = 0; i < 32; ++i) wvB[i] = W1[(k0 + 32 + i) * CDIM + t];
        #pragma unroll
        for (int i = 0; i < 8; ++i) {
            const float4 x = sv4[(k0 >> 2) + i];
            hsum = fmaf(x.x, wvA[4 * i + 0], hsum);
            hsum = fmaf(x.y, wvA[4 * i + 1], hsum);
            hsum = fmaf(x.z, wvA[4 * i + 2], hsum);
            hsum = fmaf(x.w, wvA[4 * i + 3], hsum);
        }
        if (k0 + 64 < CDIM) {
            #pragma unroll
            for (int i = 0; i < 32; ++i) wvA[i] = W1[(k0 + 64 + i) * CDIM + t];
        }
        #pragma unroll
        for (int i = 0; i < 8; ++i) {
            const float4 x = sv4[(k0 >> 2) + 8 + i];
            hsum = fmaf(x.x, wvB[4 * i + 0], hsum);
            hsum = fmaf(x.y, wvB[4 * i + 1], hsum);
            hsum = fmaf(x.z, wvB[4 * i + 2], hsum);
            hsum = fmaf(x.w, wvB[4 * i + 3], hsum);
        }
    }
    s_hid[t] = fmaxf(hsum, 0.f);
    __syncthreads();

    // ---- output heads: 16 lanes per output, batched loads + shfl reduce ----
    const int g  = t >> 4;
    const int ln = t & 15;
    const int nOut = isDet ? 15 : 43;
    const int nrep = isDet ? 1 : 3;
    for (int rep = 0; rep < nrep; ++rep) {
        const int o = g + rep * 16;
        if (o < nOut) {
            const float* Wp; int stride, oo, ooff; float bias;
            if (isDet) {
                if (o < 4) { Wp = Wcd; stride = 4;  oo = o;     ooff = pt * 4 + oo;         bias = bcd[oo]; }
                else       { Wp = Wod; stride = 11; oo = o - 4; ooff = 3600 + pt * 11 + oo; bias = bod[oo] + detfull[pt * 11 + oo]; }
            } else {
                if (o < 3) { Wp = Wcm; stride = 3;  oo = o;     ooff = 13500 + m * 3 + oo;  bias = bcm[oo]; }
                else       { Wp = Wom; stride = 40; oo = o - 3; ooff = 13800 + m * 40 + oo; bias = bom[oo] + mapanch[m * 40 + oo]; }
            }
            float wv[16], xv[16];
            #pragma unroll
            for (int kk = 0; kk < 16; ++kk) wv[kk] = Wp[(ln + kk * 16) * stride + oo];
            #pragma unroll
            for (int kk = 0; kk < 16; ++kk) xv[kk] = s_hid[ln + kk * 16];
            float sp = 0.f;
            #pragma unroll
            for (int kk = 0; kk < 16; ++kk) sp = fmaf(xv[kk], wv[kk], sp);
            #pragma unroll
            for (int off = 1; off < 16; off <<= 1) sp += __shfl_xor(sp, off, 64);
            if (ln == 0) out[ooff] = sp + bias;
        }
    }
}

extern "C" void kernel_launch(void* const* d_in, const int* in_sizes, int n_in,
                              void* d_out, int out_size, void* d_ws, size_t ws_size,
                              hipStream_t stream) {
    const float* p2      = (const float*)d_in[0];
    const float* p3      = (const float*)d_in[1];
    const float* p4      = (const float*)d_in[2];
    const float* p5      = (const float*)d_in[3];
    const float* Kin     = (const float*)d_in[4];
    const float* Ein     = (const float*)d_in[5];
    const float* det3d   = (const float*)d_in[6];
    const float* detfull = (const float*)d_in[7];
    const float* mapanch = (const float*)d_in[8];
    const float* W1d     = (const float*)d_in[9];
    const float* b1d     = (const float*)d_in[10];
    const float* Wcd     = (const float*)d_in[11];
    const float* bcd     = (const float*)d_in[12];
    const float* Wod     = (const float*)d_in[13];
    const float* bod     = (const float*)d_in[14];
    const float* W1m     = (const float*)d_in[15];
    const float* b1m     = (const float*)d_in[16];
    const float* Wcm     = (const float*)d_in[17];
    const float* bcm     = (const float*)d_in[18];
    const float* Wom     = (const float*)d_in[19];
    const float* bom     = (const float*)d_in[20];
    float* out = (float*)d_out;
    float* wsf = (float*)d_ws;   // 2.3M floats = 9.2 MB packed lvl2/3

    t_pack<<<270, 256, 0, stream>>>(p4, p5, wsf);

    autonav_fused<<<NBLK, 256, 0, stream>>>(
        p2, p3, wsf, Kin, Ein, det3d, detfull, mapanch,
        W1d, b1d, Wcd, bcd, Wod, bod, W1m, b1m, Wcm, bcm, Wom, bom, out);
}

// Round 12
// 51.793 us; speedup vs baseline: 1.5377x; 1.0478x over previous
//
#include <hip/hip_runtime.h>

#define CDIM 256
#define NDET 900
#define NMAP 100
#define NPTS 20
#define NBLK (NDET + NMAP)

// packed layouts in ws: [cam][H][W][C]
#define P4OFF 7372800    // after p3T (6*60*80*256)
#define P5OFF 9216000    // after p4T (6*30*40*256)
#define C3STR 1228800    // 60*80*256
#define C4STR 307200     // 30*40*256
#define C5STR 76800      // 15*20*256

// ---------- Kernel T: pack p3,p4,p5 into ws as [cam][H][W][C] ----------
__global__ __launch_bounds__(256) void t_pack(
    const float* __restrict__ p3, const float* __restrict__ p4,
    const float* __restrict__ p5, float* __restrict__ wsf)
{
    const int b = blockIdx.x;   // 0..359 p3, 360..539 p4, 540..629 p5
    const int t = threadIdx.x;  // channel
    if (b < 360) {
        const int cam = b / 60, h = b % 60;
        const float4* __restrict__ src = (const float4*)(p3 + ((cam * CDIM + t) * 60 + h) * 80);
        float* __restrict__ dst = wsf + ((cam * 60 + h) * 80) * CDIM + t;
        #pragma unroll
        for (int w4 = 0; w4 < 20; ++w4) {
            const float4 v = src[w4];
            dst[(w4 * 4 + 0) * CDIM] = v.x;
            dst[(w4 * 4 + 1) * CDIM] = v.y;
            dst[(w4 * 4 + 2) * CDIM] = v.z;
            dst[(w4 * 4 + 3) * CDIM] = v.w;
        }
    } else if (b < 540) {
        const int bb = b - 360;
        const int cam = bb / 30, h = bb % 30;
        const float4* __restrict__ src = (const float4*)(p4 + ((cam * CDIM + t) * 30 + h) * 40);
        float* __restrict__ dst = wsf + P4OFF + ((cam * 30 + h) * 40) * CDIM + t;
        #pragma unroll
        for (int w4 = 0; w4 < 10; ++w4) {
            const float4 v = src[w4];
            dst[(w4 * 4 + 0) * CDIM] = v.x;
            dst[(w4 * 4 + 1) * CDIM] = v.y;
            dst[(w4 * 4 + 2) * CDIM] = v.z;
            dst[(w4 * 4 + 3) * CDIM] = v.w;
        }
    } else {
        const int bb = b - 540;
        const int cam = bb / 15, h = bb % 15;
        const float4* __restrict__ src = (const float4*)(p5 + ((cam * CDIM + t) * 15 + h) * 20);
        float* __restrict__ dst = wsf + P5OFF + ((cam * 15 + h) * 20) * CDIM + t;
        #pragma unroll
        for (int w4 = 0; w4 < 5; ++w4) {
            const float4 v = src[w4];
            dst[(w4 * 4 + 0) * CDIM] = v.x;
            dst[(w4 * 4 + 1) * CDIM] = v.y;
            dst[(w4 * 4 + 2) * CDIM] = v.z;
            dst[(w4 * 4 + 3) * CDIM] = v.w;
        }
    }
}

// ---------- Kernel F: fused setup + gather + MLP + heads ----------
__global__ __launch_bounds__(256, 4) void autonav_fused(
    const float* __restrict__ p2, const float* __restrict__ wsf,
    const float* __restrict__ Kin, const float* __restrict__ Ein,
    const float* __restrict__ det3d, const float* __restrict__ detfull,
    const float* __restrict__ mapanch,
    const float* __restrict__ W1d, const float* __restrict__ b1d,
    const float* __restrict__ Wcd, const float* __restrict__ bcd,
    const float* __restrict__ Wod, const float* __restrict__ bod,
    const float* __restrict__ W1m, const float* __restrict__ b1m,
    const float* __restrict__ Wcm, const float* __restrict__ bcm,
    const float* __restrict__ Wom, const float* __restrict__ bom,
    float* __restrict__ out)
{
    const int pt = blockIdx.x;      // 0..999
    const int t  = threadIdx.x;
    const bool isDet = (pt < NDET);
    const int m = pt - NDET;

    __shared__ int   s_off[25][4];
    __shared__ float s_w[25][4];
    __shared__ int   s_list[32];
    __shared__ int   s_n;
    __shared__ float s_vec[CDIM];
    __shared__ float s_hid[CDIM];

    if (t < 25) {
        float h0, h1, h2;
        if (isDet) {
            h0 = det3d[pt * 3 + 0];
            h1 = det3d[pt * 3 + 1];
            h2 = det3d[pt * 3 + 2];
        } else {
            float cx = 0.f, cy = 0.f;
            #pragma unroll
            for (int j = 0; j < NPTS; ++j) {
                cx += mapanch[(m * NPTS + j) * 2 + 0];
                cy += mapanch[(m * NPTS + j) * 2 + 1];
            }
            h0 = cx / (float)NPTS;
            h1 = cy / (float)NPTS;
            h2 = 0.f;
        }

        bool pred = false;
        if (t < 24) {
            const int cam = t >> 2, l = t & 3;
            float pc[3];
            #pragma unroll
            for (int i = 0; i < 3; ++i) {
                pc[i] = Ein[cam * 16 + i * 4 + 0] * h0
                      + Ein[cam * 16 + i * 4 + 1] * h1
                      + Ein[cam * 16 + i * 4 + 2] * h2
                      + Ein[cam * 16 + i * 4 + 3] * 1.f;
            }
            const float q0 = Kin[cam*9+0]*pc[0] + Kin[cam*9+1]*pc[1] + Kin[cam*9+2]*pc[2];
            const float q1 = Kin[cam*9+3]*pc[0] + Kin[cam*9+4]*pc[1] + Kin[cam*9+5]*pc[2];
            const float q2 = Kin[cam*9+6]*pc[0] + Kin[cam*9+7]*pc[1] + Kin[cam*9+8]*pc[2];
            const float depth = q2;
            const float u = q0 / (depth + 1e-6f);
            const float v = q1 / (depth + 1e-6f);
            const bool valid = (depth > 0.1f);
            const float gx = u / 640.0f * 2.0f - 1.0f;
            const float gy = v / 480.0f * 2.0f - 1.0f;

            const int Hs[4] = {120, 60, 30, 15};
            const int Ws[4] = {160, 80, 40, 20};
            const int H = Hs[l], W = Ws[l];
            const float x = (gx + 1.f) * (W * 0.5f) - 0.5f;
            const float y = (gy + 1.f) * (H * 0.5f) - 0.5f;
            const float x0f = floorf(x), y0f = floorf(y);
            const float wx1 = x - x0f, wx0 = 1.f - wx1;
            const float wy1 = y - y0f, wy0 = 1.f - wy1;
            const float x1f = x0f + 1.f, y1f = y0f + 1.f;
            const bool bx0 = (x0f >= 0.f) && (x0f <= (float)(W - 1));
            const bool bx1 = (x1f >= 0.f) && (x1f <= (float)(W - 1));
            const bool by0 = (y0f >= 0.f) && (y0f <= (float)(H - 1));
            const bool by1 = (y1f >= 0.f) && (y1f <= (float)(H - 1));
            const int xc0 = (int)fminf(fmaxf(x0f, 0.f), (float)(W - 1));
            const int xc1 = (int)fminf(fmaxf(x1f, 0.f), (float)(W - 1));
            const int yc0 = (int)fminf(fmaxf(y0f, 0.f), (float)(H - 1));
            const int yc1 = (int)fminf(fmaxf(y1f, 0.f), (float)(H - 1));
            if (l == 0) {
                // p2 channel-major: gather adds t*19200
                const int base = cam * CDIM * H * W;
                s_off[t][0] = base + yc0 * W + xc0;
                s_off[t][1] = base + yc0 * W + xc1;
                s_off[t][2] = base + yc1 * W + xc0;
                s_off[t][3] = base + yc1 * W + xc1;
            } else {
                // packed [cam][H][W][C] in ws: gather adds t
                const int pb = (l == 1) ? cam * C3STR
                             : (l == 2) ? (P4OFF + cam * C4STR)
                                        : (P5OFF + cam * C5STR);
                s_off[t][0] = pb + (yc0 * W + xc0) * CDIM;
                s_off[t][1] = pb + (yc0 * W + xc1) * CDIM;
                s_off[t][2] = pb + (yc1 * W + xc0) * CDIM;
                s_off[t][3] = pb + (yc1 * W + xc1) * CDIM;
            }
            const float w0 = (bx0 && by0) ? wx0 * wy0 : 0.f;
            const float w1 = (bx1 && by0) ? wx1 * wy0 : 0.f;
            const float w2 = (bx0 && by1) ? wx0 * wy1 : 0.f;
            const float w3 = (bx1 && by1) ? wx1 * wy1 : 0.f;
            s_w[t][0] = w0; s_w[t][1] = w1; s_w[t][2] = w2; s_w[t][3] = w3;
            pred = valid && ((w0 + w1 + w2 + w3) != 0.f);
        } else {
            // dummy tile 24: packed path (coalesced wsf[t]), weight 0
            s_off[24][0] = 0; s_off[24][1] = 0; s_off[24][2] = 0; s_off[24][3] = 0;
            s_w[24][0] = 0.f; s_w[24][1] = 0.f; s_w[24][2] = 0.f; s_w[24][3] = 0.f;
        }

        const unsigned long long mask = __ballot(pred);
        const int n = __popcll(mask);
        const int rank = __popcll(mask & ((1ull << t) - 1ull));
        if (pred) s_list[rank] = t;
        const int npad = (n + 7) & ~7;
        if (t < 8 && (n + t) < npad) s_list[n + t] = 24;
        if (t == 0) s_n = npad;
    }
    __syncthreads();

    // ---- gather: branch-free chunks of 8; only l==0 (p2) is divergent ----
    float acc = 0.f;
    const int npad = s_n;
    for (int base = 0; base < npad; base += 8) {
        float v[8][4];
        int tj[8];
        #pragma unroll
        for (int j = 0; j < 8; ++j) {
            const int tt = s_list[base + j];
            tj[j] = tt;
            const bool isP2 = (tt < 24) && ((tt & 3) == 0);
            const float* f = isP2 ? p2 : wsf;
            const int coff = isP2 ? t * 19200 : t;
            v[j][0] = f[s_off[tt][0] + coff];
            v[j][1] = f[s_off[tt][1] + coff];
            v[j][2] = f[s_off[tt][2] + coff];
            v[j][3] = f[s_off[tt][3] + coff];
        }
        #pragma unroll
        for (int j = 0; j < 8; ++j) {
            const int tt = tj[j];
            acc += s_w[tt][0] * v[j][0] + s_w[tt][1] * v[j][1]
                 + s_w[tt][2] * v[j][2] + s_w[tt][3] * v[j][3];
        }
    }
    const float agg = (acc * 0.25f) / 6.0f;

    s_vec[t] = agg;
    __syncthreads();

    // ---- hidden GEMV: double-buffered 32-deep W1 batches ----
    const float* __restrict__ W1 = isDet ? W1d : W1m;
    const float* __restrict__ b1 = isDet ? b1d : b1m;
    float hsum = b1[t];
    const float4* sv4 = (const float4*)s_vec;
    float wvA[32], wvB[32];
    #pragma unroll
    for (int i = 0; i < 32; ++i) wvA[i] = W1[i * CDIM + t];
    #pragma unroll
    for (int k0 = 0; k0 < CDIM; k0 += 64) {
        #pragma unroll
        for (int i = 0; i < 32; ++i) wvB[i] = W1[(k0 + 32 + i) * CDIM + t];
        #pragma unroll
        for (int i = 0; i < 8; ++i) {
            const float4 x = sv4[(k0 >> 2) + i];
            hsum = fmaf(x.x, wvA[4 * i + 0], hsum);
            hsum = fmaf(x.y, wvA[4 * i + 1], hsum);
            hsum = fmaf(x.z, wvA[4 * i + 2], hsum);
            hsum = fmaf(x.w, wvA[4 * i + 3], hsum);
        }
        if (k0 + 64 < CDIM) {
            #pragma unroll
            for (int i = 0; i < 32; ++i) wvA[i] = W1[(k0 + 64 + i) * CDIM + t];
        }
        #pragma unroll
        for (int i = 0; i < 8; ++i) {
            const float4 x = sv4[(k0 >> 2) + 8 + i];
            hsum = fmaf(x.x, wvB[4 * i + 0], hsum);
            hsum = fmaf(x.y, wvB[4 * i + 1], hsum);
            hsum = fmaf(x.z, wvB[4 * i + 2], hsum);
            hsum = fmaf(x.w, wvB[4 * i + 3], hsum);
        }
    }
    s_hid[t] = fmaxf(hsum, 0.f);
    __syncthreads();

    // ---- output heads: 16 lanes per output, batched loads + shfl reduce ----
    const int g  = t >> 4;
    const int ln = t & 15;
    const int nOut = isDet ? 15 : 43;
    const int nrep = isDet ? 1 : 3;
    for (int rep = 0; rep < nrep; ++rep) {
        const int o = g + rep * 16;
        if (o < nOut) {
            const float* Wp; int stride, oo, ooff; float bias;
            if (isDet) {
                if (o < 4) { Wp = Wcd; stride = 4;  oo = o;     ooff = pt * 4 + oo;         bias = bcd[oo]; }
                else       { Wp = Wod; stride = 11; oo = o - 4; ooff = 3600 + pt * 11 + oo; bias = bod[oo] + detfull[pt * 11 + oo]; }
            } else {
                if (o < 3) { Wp = Wcm; stride = 3;  oo = o;     ooff = 13500 + m * 3 + oo;  bias = bcm[oo]; }
                else       { Wp = Wom; stride = 40; oo = o - 3; ooff = 13800 + m * 40 + oo; bias = bom[oo] + mapanch[m * 40 + oo]; }
            }
            float wv[16], xv[16];
            #pragma unroll
            for (int kk = 0; kk < 16; ++kk) wv[kk] = Wp[(ln + kk * 16) * stride + oo];
            #pragma unroll
            for (int kk = 0; kk < 16; ++kk) xv[kk] = s_hid[ln + kk * 16];
            float sp = 0.f;
            #pragma unroll
            for (int kk = 0; kk < 16; ++kk) sp = fmaf(xv[kk], wv[kk], sp);
            #pragma unroll
            for (int off = 1; off < 16; off <<= 1) sp += __shfl_xor(sp, off, 64);
            if (ln == 0) out[ooff] = sp + bias;
        }
    }
}

extern "C" void kernel_launch(void* const* d_in, const int* in_sizes, int n_in,
                              void* d_out, int out_size, void* d_ws, size_t ws_size,
                              hipStream_t stream) {
    const float* p2      = (const float*)d_in[0];
    const float* p3      = (const float*)d_in[1];
    const float* p4      = (const float*)d_in[2];
    const float* p5      = (const float*)d_in[3];
    const float* Kin     = (const float*)d_in[4];
    const float* Ein     = (const float*)d_in[5];
    const float* det3d   = (const float*)d_in[6];
    const float* detfull = (const float*)d_in[7];
    const float* mapanch = (const float*)d_in[8];
    const float* W1d     = (const float*)d_in[9];
    const float* b1d     = (const float*)d_in[10];
    const float* Wcd     = (const float*)d_in[11];
    const float* bcd     = (const float*)d_in[12];
    const float* Wod     = (const float*)d_in[13];
    const float* bod     = (const float*)d_in[14];
    const float* W1m     = (const float*)d_in[15];
    const float* b1m     = (const float*)d_in[16];
    const float* Wcm     = (const float*)d_in[17];
    const float* bcm     = (const float*)d_in[18];
    const float* Wom     = (const float*)d_in[19];
    const float* bom     = (const float*)d_in[20];
    float* out = (float*)d_out;
    float* wsf = (float*)d_ws;   // 9.68M floats = 38.7 MB packed p3/p4/p5

    t_pack<<<630, 256, 0, stream>>>(p3, p4, p5, wsf);

    autonav_fused<<<NBLK, 256, 0, stream>>>(
        p2, wsf, Kin, Ein, det3d, detfull, mapanch,
        W1d, b1d, Wcd, bcd, Wod, bod, W1m, b1m, Wcm, bcm, Wom, bom, out);
}